// Round 1
// baseline (128.764 us; speedup 1.0000x reference)
//
#include <hip/hip_runtime.h>
#include <float.h>

// Problem constants (from reference): B=4, N=8, C=256, H=128, W=128, D=128
#define B_ 4
#define N_ 8
#define C_ 256
#define H_ 128
#define W_ 128
#define D_ 128

// Module-scope scratch for the pooled features (32 boxes x 256 ch = 32 KB).
// Deliberately NOT d_ws: the harness poisons the 256 MB workspace every timed
// iteration (the ~42 us fillBufferAligned dispatches in rocprof). This buffer
// is fully rewritten by roi_pool_kernel before mlp_kernel reads it within the
// same iteration, so no stale-data reliance. Kernel-boundary release/acquire
// on the stream handles cross-XCD L2 visibility.
__device__ __align__(16) float pooled_g[B_ * N_ * C_];

// ---------------------------------------------------------------------------
// Kernel 1: ROI max-pool.
// grid = 32 boxes * 64 channel-groups = 2048 blocks, 256 threads (4 waves).
// Each wave handles one channel of one box. Division-free: since the setup
// guarantees rw = 2*hw+1 <= 39 < 64, each lane owns at most one column and we
// walk rows with a pointer increment (load + fmax + add per row, no idiv).
// ---------------------------------------------------------------------------
__global__ __launch_bounds__(256) void roi_pool_kernel(
    const float* __restrict__ enc,     // [B][C][H][W]
    const float* __restrict__ bboxes)  // [B][N][4]
{
    const int block = blockIdx.x;
    const int box   = block >> 6;     // 0..31  (= b*N + n)
    const int cg    = block & 63;     // channel group of 4
    const int wave  = threadIdx.x >> 6;
    const int lane  = threadIdx.x & 63;
    const int c     = cg * 4 + wave;
    const int b     = box >> 3;       // box / N

    const float* bb = bboxes + box * 4;
    // Replicate reference exactly: truncate-to-int, then integer div by 2.
    const int xc = (int)(bb[0] * (float)W_);
    const int yc = (int)(bb[1] * (float)H_);
    const int hw = ((int)(bb[2] * (float)W_)) / 2;
    const int hh = ((int)(bb[3] * (float)H_)) / 2;
    int x0 = xc - hw, x1 = xc + hw;   // inclusive
    int y0 = yc - hh, y1 = yc + hh;   // inclusive
    x0 = max(0, x0); x1 = min(W_ - 1, x1);
    y0 = max(0, y0); y1 = min(H_ - 1, y1);
    const int rw = x1 - x0 + 1;       // <= 39 by construction
    const int rh = y1 - y0 + 1;

    const float* row = enc + ((b * C_ + c) * H_ + y0) * W_ + x0;
    float m = -FLT_MAX;
    for (int y = 0; y < rh; ++y) {
        // rw < 64 always -> inner loop runs 0 or 1 times per lane; kept as a
        // strided loop purely for safety. Loads across rows are independent
        // so the compiler pipelines them.
        for (int col = lane; col < rw; col += 64)
            m = fmaxf(m, row[col]);
        row += W_;
    }
    // wave-wide max reduce (wave = 64 lanes on gfx950)
    #pragma unroll
    for (int off = 32; off; off >>= 1)
        m = fmaxf(m, __shfl_down(m, off));
    if (lane == 0)
        pooled_g[box * C_ + c] = m;
}

// ---------------------------------------------------------------------------
// Kernel 2: fused MLP.  grid = 32 blocks (one per box), 256 threads (4 waves).
// GEMM1: wave w computes h1 rows j = w*32..w*32+31. Each row is one fully
// coalesced float4 wave-load of w1 (64 lanes x 16 B = the whole 1 KB row),
// dotted against a register-held float4 slice of pooled, then shfl-reduced.
// (The old layout read w1 at 1 KB lane stride: 64 cache lines per load.)
// GEMM2 + sigmoid: wave 0 reduces the 4 outputs. Output transposed: [N][B][4].
// ---------------------------------------------------------------------------
__global__ __launch_bounds__(256) void mlp_kernel(
    const float* __restrict__ w1,      // [128][256]
    const float* __restrict__ b1,      // [128]
    const float* __restrict__ w2,      // [4][128]
    const float* __restrict__ b2,      // [4]
    float* __restrict__ out)           // [N][B][4]
{
    const int i    = blockIdx.x;       // box index = b*N + n
    const int wave = threadIdx.x >> 6; // 0..3
    const int lane = threadIdx.x & 63;

    __shared__ float h1_s[D_];

    // Each lane holds one float4 chunk of this box's pooled row
    // (64 lanes * 4 floats = 256 = C). One coalesced load, reused 32 times.
    const float4 pp = ((const float4*)(pooled_g + i * C_))[lane];

    const float4* w1v = (const float4*)w1;
    for (int r = 0; r < 32; ++r) {
        const int j = wave * 32 + r;
        const float4 wv = w1v[j * 64 + lane];   // coalesced: whole row j
        float s = wv.x * pp.x + wv.y * pp.y + wv.z * pp.z + wv.w * pp.w;
        #pragma unroll
        for (int off = 32; off; off >>= 1)
            s += __shfl_down(s, off);
        if (lane == 0)
            h1_s[j] = s + b1[j];
    }
    __syncthreads();

    if (wave == 0) {
        #pragma unroll
        for (int jo = 0; jo < 4; ++jo) {
            float part = h1_s[lane]      * w2[jo * D_ + lane]
                       + h1_s[lane + 64] * w2[jo * D_ + lane + 64];
            #pragma unroll
            for (int off = 32; off; off >>= 1)
                part += __shfl_down(part, off);
            if (lane == 0) {
                const int b = i >> 3;   // i / N
                const int n = i & 7;    // i % N
                const float v = part + b2[jo];
                out[(n * B_ + b) * 4 + jo] = 1.0f / (1.0f + expf(-v));
            }
        }
    }
}

extern "C" void kernel_launch(void* const* d_in, const int* in_sizes, int n_in,
                              void* d_out, int out_size, void* d_ws, size_t ws_size,
                              hipStream_t stream) {
    const float* encoded = (const float*)d_in[0];  // [B][C][H][W]
    const float* bboxes  = (const float*)d_in[1];  // [B][N][4]
    const float* w1      = (const float*)d_in[2];  // [D][C]
    const float* b1      = (const float*)d_in[3];  // [D]
    const float* w2      = (const float*)d_in[4];  // [4][D]
    const float* b2      = (const float*)d_in[5];  // [4]
    float* out = (float*)d_out;                    // [N][B][4] = 128 floats
    (void)d_ws; (void)ws_size;                     // workspace deliberately unused

    roi_pool_kernel<<<dim3(B_ * N_ * (C_ / 4)), dim3(256), 0, stream>>>(
        encoded, bboxes);
    mlp_kernel<<<dim3(B_ * N_), dim3(256), 0, stream>>>(
        w1, b1, w2, b2, out);
}